// Round 1
// baseline (261.412 us; speedup 1.0000x reference)
//
#include <hip/hip_runtime.h>
#include <cmath>

#define BATCH 8
#define SEQ   2048
#define NEMB  2048
#define HD    128

typedef __bf16 v8bf __attribute__((ext_vector_type(8)));
typedef float  f32x4 __attribute__((ext_vector_type(4)));

union U8 { v8bf v; __bf16 b[8]; unsigned short e[8]; };

// ---------------- QKV projection ----------------
// C[m][n] = sum_k x[m][k] * W[n][k] + bias[n]  -> bf16 (Q/K/V in workspace)
// grid: 128 M-tiles * 3 projections (proj fastest for L2/L3 reuse of x), 256 thr
__global__ __launch_bounds__(256) void qkv_proj_kernel(
    const float* __restrict__ x,
    const float* __restrict__ Wq, const float* __restrict__ bq,
    const float* __restrict__ Wk, const float* __restrict__ bk,
    const float* __restrict__ Wv, const float* __restrict__ bv,
    __bf16* __restrict__ Qb, __bf16* __restrict__ Kb, __bf16* __restrict__ Vb)
{
  const int bid = blockIdx.x;
  const int mt = bid / 3;
  const int proj = bid % 3;
  const float* __restrict__ W    = (proj == 0) ? Wq : (proj == 1) ? Wk : Wv;
  const float* __restrict__ bias = (proj == 0) ? bq : (proj == 1) ? bk : bv;
  __bf16* __restrict__ Out       = (proj == 0) ? Qb : (proj == 1) ? Kb : Vb;
  const int m0 = mt * 128;

  __shared__ __bf16 Asm[128 * 64];  // x tile, row-major 64 bf16/row, XOR-swizzled
  __shared__ __bf16 Bsm[128 * 64];  // W tile

  const int t = threadIdx.x;
  const int lane = t & 63;
  const int w = t >> 6;
  const int wm = w >> 1, wn = w & 1;     // 2x2 wave grid, each wave 64x64
  const int hi = lane >> 4, lo = lane & 15;

  const int srow  = t >> 1;              // staging row 0..127
  const int shalf = t & 1;               // 32-col half
  const int sw = (srow & 7) << 4;

  f32x4 acc[4][4];
  const f32x4 fz = {0.f, 0.f, 0.f, 0.f};
#pragma unroll
  for (int m = 0; m < 4; ++m)
#pragma unroll
    for (int n = 0; n < 4; ++n) acc[m][n] = fz;

  const float* xrow = x + (size_t)(m0 + srow) * NEMB + shalf * 32;
  const float* wrow = W + (size_t)srow * NEMB + shalf * 32;

  for (int k0 = 0; k0 < NEMB; k0 += 64) {
    __syncthreads();
    {
      const float4* a4 = (const float4*)(xrow + k0);
      const float4* b4 = (const float4*)(wrow + k0);
      float fa[32], fb[32];
      float4* fav = (float4*)fa; float4* fbv = (float4*)fb;
#pragma unroll
      for (int j = 0; j < 8; ++j) { fav[j] = a4[j]; fbv[j] = b4[j]; }
      const int rb = srow * 128;
#pragma unroll
      for (int jj = 0; jj < 4; ++jj) {
        U8 ua, ub;
#pragma unroll
        for (int i = 0; i < 8; ++i) { ua.b[i] = (__bf16)fa[jj*8+i]; ub.b[i] = (__bf16)fb[jj*8+i]; }
        const int byte = rb + ((shalf * 64 + jj * 16) ^ sw);
        *(v8bf*)((char*)Asm + byte) = ua.v;
        *(v8bf*)((char*)Bsm + byte) = ub.v;
      }
    }
    __syncthreads();
#pragma unroll
    for (int kk = 0; kk < 2; ++kk) {
      const int cb = kk * 64 + hi * 16;  // byte col of 8-elem k-chunk
      v8bf a[4], b[4];
#pragma unroll
      for (int m = 0; m < 4; ++m) {
        const int r = wm * 64 + m * 16 + lo;
        a[m] = *(const v8bf*)((const char*)Asm + r * 128 + (cb ^ ((r & 7) << 4)));
      }
#pragma unroll
      for (int n = 0; n < 4; ++n) {
        const int r = wn * 64 + n * 16 + lo;
        b[n] = *(const v8bf*)((const char*)Bsm + r * 128 + (cb ^ ((r & 7) << 4)));
      }
#pragma unroll
      for (int m = 0; m < 4; ++m)
#pragma unroll
        for (int n = 0; n < 4; ++n)
          acc[m][n] = __builtin_amdgcn_mfma_f32_16x16x32_bf16(a[m], b[n], acc[m][n], 0, 0, 0);
    }
  }
#pragma unroll
  for (int n = 0; n < 4; ++n) {
    const int col = wn * 64 + n * 16 + lo;
    const float bi = bias[col];
#pragma unroll
    for (int m = 0; m < 4; ++m) {
#pragma unroll
      for (int r = 0; r < 4; ++r) {
        const int row = m0 + wm * 64 + m * 16 + hi * 4 + r;
        Out[(size_t)row * HD + col] = (__bf16)(acc[m][n][r] + bi);
      }
    }
  }
}

// ---------------- Flash attention (causal) ----------------
// grid: 8 batches * 32 q-tiles of 64 rows, 256 thr (4 waves x 16 q-rows)
__global__ __launch_bounds__(256) void attn_kernel(
    const __bf16* __restrict__ Qb, const __bf16* __restrict__ Kb,
    const __bf16* __restrict__ Vb, float* __restrict__ out)
{
  const int bid = blockIdx.x;
  const int b = bid >> 5;
  const int qt = bid & 31;
  const int q0 = qt * 64;
  const int t = threadIdx.x;
  const int lane = t & 63;
  const int w = t >> 6;
  const int hi = lane >> 4, lo = lane & 15;

  __shared__ __bf16 Ksm[64 * 128];   // [key][d], swizzled
  __shared__ __bf16 Vtsm[128 * 64];  // [d][key], swizzled
  __shared__ __bf16 Psm[4][16 * 64]; // per-wave P tile [qrow][key], swizzled

  // Q fragments (A operand): row = lane&15, k = (lane>>4)*8+i (+32 per kk)
  v8bf aQ[4];
  {
    const __bf16* qp = Qb + ((size_t)(b * SEQ + q0 + w * 16 + lo)) * HD + hi * 8;
#pragma unroll
    for (int kk = 0; kk < 4; ++kk) aQ[kk] = *(const v8bf*)(qp + kk * 32);
  }

  f32x4 accO[8];
  const f32x4 fz = {0.f, 0.f, 0.f, 0.f};
#pragma unroll
  for (int n = 0; n < 8; ++n) accO[n] = fz;
  float m_s[4], l_s[4];
#pragma unroll
  for (int r = 0; r < 4; ++r) { m_s[r] = -INFINITY; l_s[r] = 0.f; }

  const float scale = 0.022097086912079608f; // 1/sqrt(2048)

  for (int kv = 0; kv <= qt; ++kv) {
    __syncthreads();
    // stage K tile [64][128]
    {
      const int key = t >> 2, dc = t & 3;
      const __bf16* kp = Kb + ((size_t)(b * SEQ + kv * 64 + key)) * HD + dc * 32;
      const int rb = key * 256;
      const int swk = (key & 7) << 4;
#pragma unroll
      for (int j = 0; j < 4; ++j) {
        v8bf v = *(const v8bf*)(kp + j * 8);
        *(v8bf*)((char*)Ksm + rb + ((dc * 64 + j * 16) ^ swk)) = v;
      }
    }
    // stage V transposed: Vt[d][key]
    {
      const int keyg = t >> 4, dg = t & 15;
      const __bf16* vp = Vb + ((size_t)(b * SEQ + kv * 64 + keyg * 4)) * HD + dg * 8;
      U8 vv[4];
#pragma unroll
      for (int j = 0; j < 4; ++j) vv[j].v = *(const v8bf*)(vp + (size_t)j * HD);
#pragma unroll
      for (int d = 0; d < 8; ++d) {
        ushort4 pk = make_ushort4(vv[0].e[d], vv[1].e[d], vv[2].e[d], vv[3].e[d]);
        const int row = dg * 8 + d;
        *(ushort4*)((char*)Vtsm + row * 128 + ((keyg * 8) ^ ((d & 7) << 4))) = pk;
      }
    }
    __syncthreads();

    // S = Q K^T : 16x64 per wave
    f32x4 accS[4];
#pragma unroll
    for (int n = 0; n < 4; ++n) accS[n] = fz;
#pragma unroll
    for (int kk = 0; kk < 4; ++kk) {
      const int cb = kk * 64 + hi * 16;
      v8bf bk[4];
#pragma unroll
      for (int n = 0; n < 4; ++n) {
        const int r = n * 16 + lo;
        bk[n] = *(const v8bf*)((const char*)Ksm + r * 256 + (cb ^ ((r & 7) << 4)));
      }
#pragma unroll
      for (int n = 0; n < 4; ++n)
        accS[n] = __builtin_amdgcn_mfma_f32_16x16x32_bf16(aQ[kk], bk[n], accS[n], 0, 0, 0);
    }

    // scale + causal mask (diagonal tile only)
    float s[4][4];
    const bool diag = (kv == qt);
#pragma unroll
    for (int n = 0; n < 4; ++n)
#pragma unroll
      for (int r = 0; r < 4; ++r) {
        float v = accS[n][r] * scale;
        if (diag) {
          const int key = kv * 64 + n * 16 + lo;
          const int qr = q0 + w * 16 + hi * 4 + r;
          if (key > qr) v = -INFINITY;
        }
        s[n][r] = v;
      }

    // online softmax (rows live on 16-lane groups)
    float mx[4];
#pragma unroll
    for (int r = 0; r < 4; ++r) {
      mx[r] = fmaxf(fmaxf(s[0][r], s[1][r]), fmaxf(s[2][r], s[3][r]));
#pragma unroll
      for (int off = 1; off < 16; off <<= 1)
        mx[r] = fmaxf(mx[r], __shfl_xor(mx[r], off));
    }
    float corr[4], p[4][4], rs[4];
#pragma unroll
    for (int r = 0; r < 4; ++r) {
      const float mnew = fmaxf(m_s[r], mx[r]);
      corr[r] = __expf(m_s[r] - mnew);
      m_s[r] = mnew;
      rs[r] = 0.f;
    }
#pragma unroll
    for (int n = 0; n < 4; ++n)
#pragma unroll
      for (int r = 0; r < 4; ++r) {
        p[n][r] = __expf(s[n][r] - m_s[r]);
        rs[r] += p[n][r];
      }
#pragma unroll
    for (int r = 0; r < 4; ++r) {
#pragma unroll
      for (int off = 1; off < 16; off <<= 1) rs[r] += __shfl_xor(rs[r], off);
      l_s[r] = l_s[r] * corr[r] + rs[r];
    }
#pragma unroll
    for (int n = 0; n < 8; ++n)
#pragma unroll
      for (int r = 0; r < 4; ++r) accO[n][r] *= corr[r];

    // P -> per-wave LDS (bf16), to reach A-frag layout
#pragma unroll
    for (int n = 0; n < 4; ++n)
#pragma unroll
      for (int r = 0; r < 4; ++r) {
        const int row = hi * 4 + r;
        __bf16 h = (__bf16)p[n][r];
        *(unsigned short*)((char*)&Psm[w][0] + row * 128 +
                           (((n * 16 + lo) * 2) ^ ((row & 7) << 4))) =
            __builtin_bit_cast(unsigned short, h);
      }

    // O += P V
#pragma unroll
    for (int k2 = 0; k2 < 2; ++k2) {
      const int cb = k2 * 64 + hi * 16;
      const v8bf aP = *(const v8bf*)((const char*)&Psm[w][0] + lo * 128 + (cb ^ ((lo & 7) << 4)));
#pragma unroll
      for (int n = 0; n < 8; ++n) {
        const int r = n * 16 + lo;
        const v8bf bv = *(const v8bf*)((const char*)Vtsm + r * 128 + (cb ^ ((r & 7) << 4)));
        accO[n] = __builtin_amdgcn_mfma_f32_16x16x32_bf16(aP, bv, accO[n], 0, 0, 0);
      }
    }
  }

  // normalize + store fp32
#pragma unroll
  for (int r = 0; r < 4; ++r) {
    const float inv = 1.f / l_s[r];
    const int qr = q0 + w * 16 + hi * 4 + r;
    float* op = out + ((size_t)(b * SEQ + qr)) * HD + lo;
#pragma unroll
    for (int n = 0; n < 8; ++n) op[n * 16] = accO[n][r] * inv;
  }
}

extern "C" void kernel_launch(void* const* d_in, const int* in_sizes, int n_in,
                              void* d_out, int out_size, void* d_ws, size_t ws_size,
                              hipStream_t stream) {
  const float* x  = (const float*)d_in[0];
  const float* Wq = (const float*)d_in[1];
  const float* bq = (const float*)d_in[2];
  const float* Wk = (const float*)d_in[3];
  const float* bk = (const float*)d_in[4];
  const float* Wv = (const float*)d_in[5];
  const float* bv = (const float*)d_in[6];
  float* out = (float*)d_out;

  __bf16* Qb = (__bf16*)d_ws;                       // 16384x128 bf16
  __bf16* Kb = Qb + (size_t)BATCH * SEQ * HD;
  __bf16* Vb = Kb + (size_t)BATCH * SEQ * HD;

  qkv_proj_kernel<<<dim3(128 * 3), dim3(256), 0, stream>>>(
      x, Wq, bq, Wk, bk, Wv, bv, Qb, Kb, Vb);
  attn_kernel<<<dim3(BATCH * (SEQ / 64)), dim3(256), 0, stream>>>(Qb, Kb, Vb, out);
}

// Round 2
// 221.791 us; speedup vs baseline: 1.1786x; 1.1786x over previous
//
#include <hip/hip_runtime.h>
#include <cmath>

#define BATCH 8
#define SEQ   2048
#define NEMB  2048
#define HD    128

typedef __bf16 v8bf __attribute__((ext_vector_type(8)));
typedef float  f32x4 __attribute__((ext_vector_type(4)));

union U8 { v8bf v; __bf16 b[8]; unsigned short e[8]; };

__device__ inline v8bf cvt8(float4 a, float4 b) {
  U8 u;
  u.b[0] = (__bf16)a.x; u.b[1] = (__bf16)a.y; u.b[2] = (__bf16)a.z; u.b[3] = (__bf16)a.w;
  u.b[4] = (__bf16)b.x; u.b[5] = (__bf16)b.y; u.b[6] = (__bf16)b.z; u.b[7] = (__bf16)b.w;
  return u.v;
}

// ---------------- QKV projection ----------------
// C[m][n] = sum_k x[m][k] * W[n][k] + bias[n]  -> bf16
// Mtile=64, BK=64, 4 waves (2x2), double-buffered LDS + depth-1 reg prefetch.
// grid: 256 M-tiles * 3 projections; XCD-chunked swizzle so the 3 projections
// of one x-tile share an XCD's L2.
__global__ __launch_bounds__(256) void qkv_proj_kernel(
    const float* __restrict__ x,
    const float* __restrict__ Wq, const float* __restrict__ bq,
    const float* __restrict__ Wk, const float* __restrict__ bk,
    const float* __restrict__ Wv, const float* __restrict__ bv,
    __bf16* __restrict__ Qb, __bf16* __restrict__ Kb, __bf16* __restrict__ Vb)
{
  // 768 blocks; bijective XCD swizzle (768 % 8 == 0, chunk = 96)
  const int bid0 = blockIdx.x;
  const int bid = ((bid0 & 7) * 96) + (bid0 >> 3);
  const int mt = bid / 3;
  const int proj = bid % 3;
  const float* __restrict__ W    = (proj == 0) ? Wq : (proj == 1) ? Wk : Wv;
  const float* __restrict__ bias = (proj == 0) ? bq : (proj == 1) ? bk : bv;
  __bf16* __restrict__ Out       = (proj == 0) ? Qb : (proj == 1) ? Kb : Vb;
  const int m0 = mt * 64;

  __shared__ __bf16 Asm[2][64 * 64];   // x tile, 128B rows, XOR-swizzled
  __shared__ __bf16 Bsm[2][128 * 64];  // W tile

  const int t = threadIdx.x;
  const int lane = t & 63;
  const int w = t >> 6;
  const int wm = w >> 1, wn = w & 1;   // wave: rows wm*32.., cols wn*64..
  const int hi = lane >> 4, lo = lane & 15;

  // staging mapping
  const int arow = t >> 2, aq = t & 3;   // A: 4 lanes/row, 16 fp32 each
  const int brow = t >> 1, bh = t & 1;   // B: 2 lanes/row, 32 fp32 each
  const float* aptr = x + (size_t)(m0 + arow) * NEMB + aq * 16;
  const float* bptr = W + (size_t)brow * NEMB + bh * 32;
  const int aswz = (arow & 7) << 4;
  const int bswz = (brow & 7) << 4;

  f32x4 acc[2][4];
  const f32x4 fz = {0.f, 0.f, 0.f, 0.f};
#pragma unroll
  for (int m = 0; m < 2; ++m)
#pragma unroll
    for (int n = 0; n < 4; ++n) acc[m][n] = fz;

  float4 ra[4], rb[8];

  auto LOAD = [&](int tt) {
    const int k0 = tt * 64;
#pragma unroll
    for (int j = 0; j < 4; ++j) ra[j] = *(const float4*)(aptr + k0 + j * 4);
#pragma unroll
    for (int j = 0; j < 8; ++j) rb[j] = *(const float4*)(bptr + k0 + j * 4);
  };
  auto CVTW = [&](int buf) {
    char* ab = (char*)&Asm[buf][0];
    char* bb = (char*)&Bsm[buf][0];
#pragma unroll
    for (int c = 0; c < 2; ++c)
      *(v8bf*)(ab + arow * 128 + ((aq * 32 + c * 16) ^ aswz)) = cvt8(ra[2 * c], ra[2 * c + 1]);
#pragma unroll
    for (int c = 0; c < 4; ++c)
      *(v8bf*)(bb + brow * 128 + ((bh * 64 + c * 16) ^ bswz)) = cvt8(rb[2 * c], rb[2 * c + 1]);
  };
  auto MFMA = [&](int buf) {
    const char* ab = (const char*)&Asm[buf][0];
    const char* bb = (const char*)&Bsm[buf][0];
#pragma unroll
    for (int kk = 0; kk < 2; ++kk) {
      const int cb = kk * 64 + hi * 16;
      v8bf a[2], b[4];
#pragma unroll
      for (int m = 0; m < 2; ++m) {
        const int r = wm * 32 + m * 16 + lo;
        a[m] = *(const v8bf*)(ab + r * 128 + (cb ^ ((r & 7) << 4)));
      }
#pragma unroll
      for (int n = 0; n < 4; ++n) {
        const int r = wn * 64 + n * 16 + lo;
        b[n] = *(const v8bf*)(bb + r * 128 + (cb ^ ((r & 7) << 4)));
      }
#pragma unroll
      for (int m = 0; m < 2; ++m)
#pragma unroll
        for (int n = 0; n < 4; ++n)
          acc[m][n] = __builtin_amdgcn_mfma_f32_16x16x32_bf16(a[m], b[n], acc[m][n], 0, 0, 0);
    }
  };

  const int NT = NEMB / 64;  // 32
  LOAD(0);
  CVTW(0);
  __syncthreads();
  for (int tt = 0; tt < NT; ++tt) {
    const int cur = tt & 1;
    if (tt + 1 < NT) LOAD(tt + 1);   // issue early: overlaps with MFMA below
    MFMA(cur);
    if (tt + 1 < NT) CVTW(cur ^ 1);  // waitcnt lands here, after MFMA issued
    __syncthreads();
  }

#pragma unroll
  for (int n = 0; n < 4; ++n) {
    const int col = wn * 64 + n * 16 + lo;
    const float bi = bias[col];
#pragma unroll
    for (int m = 0; m < 2; ++m) {
#pragma unroll
      for (int r = 0; r < 4; ++r) {
        const int row = m0 + wm * 32 + m * 16 + hi * 4 + r;
        Out[(size_t)row * HD + col] = (__bf16)(acc[m][n][r] + bi);
      }
    }
  }
}

// ---------------- Flash attention (causal) ----------------
// grid: 8 batches * 32 q-tiles of 64 rows, 256 thr (4 waves x 16 q-rows)
__global__ __launch_bounds__(256) void attn_kernel(
    const __bf16* __restrict__ Qb, const __bf16* __restrict__ Kb,
    const __bf16* __restrict__ Vb, float* __restrict__ out)
{
  // XCD swizzle: each XCD gets one batch's 32 q-tiles -> K/V L2-resident
  const int bid0 = blockIdx.x;
  const int bid = ((bid0 & 7) << 5) + (bid0 >> 3);
  const int b = bid >> 5;
  const int qt = bid & 31;
  const int q0 = qt * 64;
  const int t = threadIdx.x;
  const int lane = t & 63;
  const int w = t >> 6;
  const int hi = lane >> 4, lo = lane & 15;

  __shared__ __bf16 Ksm[64 * 128];   // [key][d], swizzled
  __shared__ __bf16 Vtsm[128 * 64];  // [d][key], swizzled
  __shared__ __bf16 Psm[4][16 * 64]; // per-wave P tile [qrow][key], swizzled

  v8bf aQ[4];
  {
    const __bf16* qp = Qb + ((size_t)(b * SEQ + q0 + w * 16 + lo)) * HD + hi * 8;
#pragma unroll
    for (int kk = 0; kk < 4; ++kk) aQ[kk] = *(const v8bf*)(qp + kk * 32);
  }

  f32x4 accO[8];
  const f32x4 fz = {0.f, 0.f, 0.f, 0.f};
#pragma unroll
  for (int n = 0; n < 8; ++n) accO[n] = fz;
  float m_s[4], l_s[4];
#pragma unroll
  for (int r = 0; r < 4; ++r) { m_s[r] = -INFINITY; l_s[r] = 0.f; }

  const float scale = 0.022097086912079608f; // 1/sqrt(2048)

  for (int kv = 0; kv <= qt; ++kv) {
    __syncthreads();
    {
      const int key = t >> 2, dc = t & 3;
      const __bf16* kp = Kb + ((size_t)(b * SEQ + kv * 64 + key)) * HD + dc * 32;
      const int rb = key * 256;
      const int swk = (key & 7) << 4;
#pragma unroll
      for (int j = 0; j < 4; ++j) {
        v8bf v = *(const v8bf*)(kp + j * 8);
        *(v8bf*)((char*)Ksm + rb + ((dc * 64 + j * 16) ^ swk)) = v;
      }
    }
    {
      const int keyg = t >> 4, dg = t & 15;
      const __bf16* vp = Vb + ((size_t)(b * SEQ + kv * 64 + keyg * 4)) * HD + dg * 8;
      U8 vv[4];
#pragma unroll
      for (int j = 0; j < 4; ++j) vv[j].v = *(const v8bf*)(vp + (size_t)j * HD);
#pragma unroll
      for (int d = 0; d < 8; ++d) {
        ushort4 pk = make_ushort4(vv[0].e[d], vv[1].e[d], vv[2].e[d], vv[3].e[d]);
        const int row = dg * 8 + d;
        *(ushort4*)((char*)Vtsm + row * 128 + ((keyg * 8) ^ ((d & 7) << 4))) = pk;
      }
    }
    __syncthreads();

    f32x4 accS[4];
#pragma unroll
    for (int n = 0; n < 4; ++n) accS[n] = fz;
#pragma unroll
    for (int kk = 0; kk < 4; ++kk) {
      const int cb = kk * 64 + hi * 16;
      v8bf bk[4];
#pragma unroll
      for (int n = 0; n < 4; ++n) {
        const int r = n * 16 + lo;
        bk[n] = *(const v8bf*)((const char*)Ksm + r * 256 + (cb ^ ((r & 7) << 4)));
      }
#pragma unroll
      for (int n = 0; n < 4; ++n)
        accS[n] = __builtin_amdgcn_mfma_f32_16x16x32_bf16(aQ[kk], bk[n], accS[n], 0, 0, 0);
    }

    float s[4][4];
    const bool diag = (kv == qt);
#pragma unroll
    for (int n = 0; n < 4; ++n)
#pragma unroll
      for (int r = 0; r < 4; ++r) {
        float v = accS[n][r] * scale;
        if (diag) {
          const int key = kv * 64 + n * 16 + lo;
          const int qr = q0 + w * 16 + hi * 4 + r;
          if (key > qr) v = -INFINITY;
        }
        s[n][r] = v;
      }

    float mx[4];
#pragma unroll
    for (int r = 0; r < 4; ++r) {
      mx[r] = fmaxf(fmaxf(s[0][r], s[1][r]), fmaxf(s[2][r], s[3][r]));
#pragma unroll
      for (int off = 1; off < 16; off <<= 1)
        mx[r] = fmaxf(mx[r], __shfl_xor(mx[r], off));
    }
    float corr[4], p[4][4], rs[4];
#pragma unroll
    for (int r = 0; r < 4; ++r) {
      const float mnew = fmaxf(m_s[r], mx[r]);
      corr[r] = __expf(m_s[r] - mnew);
      m_s[r] = mnew;
      rs[r] = 0.f;
    }
#pragma unroll
    for (int n = 0; n < 4; ++n)
#pragma unroll
      for (int r = 0; r < 4; ++r) {
        p[n][r] = __expf(s[n][r] - m_s[r]);
        rs[r] += p[n][r];
      }
#pragma unroll
    for (int r = 0; r < 4; ++r) {
#pragma unroll
      for (int off = 1; off < 16; off <<= 1) rs[r] += __shfl_xor(rs[r], off);
      l_s[r] = l_s[r] * corr[r] + rs[r];
    }
#pragma unroll
    for (int n = 0; n < 8; ++n)
#pragma unroll
      for (int r = 0; r < 4; ++r) accO[n][r] *= corr[r];

#pragma unroll
    for (int n = 0; n < 4; ++n)
#pragma unroll
      for (int r = 0; r < 4; ++r) {
        const int row = hi * 4 + r;
        __bf16 h = (__bf16)p[n][r];
        *(unsigned short*)((char*)&Psm[w][0] + row * 128 +
                           (((n * 16 + lo) * 2) ^ ((row & 7) << 4))) =
            __builtin_bit_cast(unsigned short, h);
      }

#pragma unroll
    for (int k2 = 0; k2 < 2; ++k2) {
      const int cb = k2 * 64 + hi * 16;
      const v8bf aP = *(const v8bf*)((const char*)&Psm[w][0] + lo * 128 + (cb ^ ((lo & 7) << 4)));
#pragma unroll
      for (int n = 0; n < 8; ++n) {
        const int r = n * 16 + lo;
        const v8bf bv = *(const v8bf*)((const char*)Vtsm + r * 128 + (cb ^ ((r & 7) << 4)));
        accO[n] = __builtin_amdgcn_mfma_f32_16x16x32_bf16(aP, bv, accO[n], 0, 0, 0);
      }
    }
  }

#pragma unroll
  for (int r = 0; r < 4; ++r) {
    const float inv = 1.f / l_s[r];
    const int qr = q0 + w * 16 + hi * 4 + r;
    float* op = out + ((size_t)(b * SEQ + qr)) * HD + lo;
#pragma unroll
    for (int n = 0; n < 8; ++n) op[n * 16] = accO[n][r] * inv;
  }
}

extern "C" void kernel_launch(void* const* d_in, const int* in_sizes, int n_in,
                              void* d_out, int out_size, void* d_ws, size_t ws_size,
                              hipStream_t stream) {
  const float* x  = (const float*)d_in[0];
  const float* Wq = (const float*)d_in[1];
  const float* bq = (const float*)d_in[2];
  const float* Wk = (const float*)d_in[3];
  const float* bk = (const float*)d_in[4];
  const float* Wv = (const float*)d_in[5];
  const float* bv = (const float*)d_in[6];
  float* out = (float*)d_out;

  __bf16* Qb = (__bf16*)d_ws;                       // 16384x128 bf16
  __bf16* Kb = Qb + (size_t)BATCH * SEQ * HD;
  __bf16* Vb = Kb + (size_t)BATCH * SEQ * HD;

  qkv_proj_kernel<<<dim3(256 * 3), dim3(256), 0, stream>>>(
      x, Wq, bq, Wk, bk, Wv, bv, Qb, Kb, Vb);
  attn_kernel<<<dim3(BATCH * (SEQ / 64)), dim3(256), 0, stream>>>(Qb, Kb, Vb, out);
}

// Round 3
// 144.467 us; speedup vs baseline: 1.8095x; 1.5352x over previous
//
#include <hip/hip_runtime.h>
#include <cmath>

#define BATCH 8
#define SEQ   2048
#define NEMB  2048
#define HD    128

typedef __bf16 v8bf __attribute__((ext_vector_type(8)));
typedef float  f32x4 __attribute__((ext_vector_type(4)));

union U8 { v8bf v; __bf16 b[8]; unsigned short e[8]; };
union F4 { f32x4 v; float f[4]; };

__device__ inline void async16(void* lds, const void* g) {
  __builtin_amdgcn_global_load_lds(
      (const __attribute__((address_space(1))) unsigned int*)g,
      (__attribute__((address_space(3))) unsigned int*)lds, 16, 0, 0);
}

// ---------------- W fp32 -> bf16 (3 x 128 x 2048) ----------------
__global__ __launch_bounds__(256) void wconv_kernel(
    const float* __restrict__ Wq, const float* __restrict__ Wk,
    const float* __restrict__ Wv, __bf16* __restrict__ out) {
  const int id = blockIdx.x;                 // 3 * 64 blocks
  const int proj = id >> 6, blk = id & 63;
  const float* __restrict__ W = proj == 0 ? Wq : proj == 1 ? Wk : Wv;
  __bf16* __restrict__ o = out + (size_t)proj * (HD * NEMB);
  const int base = blk * 4096 + threadIdx.x * 16;
  const float4* s = (const float4*)(W + base);
  float4 f0 = s[0], f1 = s[1], f2 = s[2], f3 = s[3];
  U8 u0, u1;
  u0.b[0]=(__bf16)f0.x; u0.b[1]=(__bf16)f0.y; u0.b[2]=(__bf16)f0.z; u0.b[3]=(__bf16)f0.w;
  u0.b[4]=(__bf16)f1.x; u0.b[5]=(__bf16)f1.y; u0.b[6]=(__bf16)f1.z; u0.b[7]=(__bf16)f1.w;
  u1.b[0]=(__bf16)f2.x; u1.b[1]=(__bf16)f2.y; u1.b[2]=(__bf16)f2.z; u1.b[3]=(__bf16)f2.w;
  u1.b[4]=(__bf16)f3.x; u1.b[5]=(__bf16)f3.y; u1.b[6]=(__bf16)f3.z; u1.b[7]=(__bf16)f3.w;
  *(v8bf*)(o + base) = u0.v;
  *(v8bf*)(o + base + 8) = u1.v;
}

// ---------------- QKV projection ----------------
// C[m][n] = sum_k x[m][k] * W[n][k] + bias[n]  -> bf16
// Mtile=64, BK=64, 4 waves (2x2). global_load_lds (16B) staging:
//   A tile fp32 [64][64]  (16 KB, rows 256B, 16B-chunk XOR swizzle low-3-bits)
//   B tile bf16 [128][64] (16 KB, rows 128B, same swizzle)
// LDS dest linear, global source inverse-swizzled per lane (rule: both-sides).
__global__ __launch_bounds__(256, 3) void qkv_proj_kernel(
    const float* __restrict__ x, const __bf16* __restrict__ Wb,
    const float* __restrict__ bq, const float* __restrict__ bk,
    const float* __restrict__ bv,
    __bf16* __restrict__ Qb, __bf16* __restrict__ Kb, __bf16* __restrict__ Vb)
{
  // 768 blocks; bijective XCD swizzle (768 % 8 == 0, chunk = 96)
  const int bid0 = blockIdx.x;
  const int bid = ((bid0 & 7) * 96) + (bid0 >> 3);
  const int mt = bid / 3;
  const int proj = bid % 3;
  const __bf16* __restrict__ W = Wb + (size_t)proj * (HD * NEMB);
  const float* __restrict__ bias = proj == 0 ? bq : proj == 1 ? bk : bv;
  __bf16* __restrict__ Out = proj == 0 ? Qb : proj == 1 ? Kb : Vb;
  const int m0 = mt * 64;

  __shared__ float  Asm[64 * 64];    // fp32 x tile
  __shared__ __bf16 Bsm[128 * 64];   // bf16 W tile

  const int t = threadIdx.x, lane = t & 63, w = t >> 6;
  const int wm = w >> 1, wn = w & 1;
  const int hi = lane >> 4, lo = lane & 15;

  // staging pointers: 4 A-slots + 4 B-slots per wave, 1 KB each
  const float* pa[4];
  const __bf16* pb[4];
  char* la[4];
  char* lb[4];
#pragma unroll
  for (int i = 0; i < 4; ++i) {
    {  // A chunk (w*4+i): 4 rows x 256B; lane covers (row=lane>>4, col16=lane&15)
      const int r = (w * 4 + i) * 4 + (lane >> 4);
      const int c = (lane & 15) ^ (r & 7);         // inverse swizzle (bit3 preserved)
      pa[i] = x + (size_t)(m0 + r) * NEMB + c * 4;
      la[i] = (char*)Asm + (w * 4 + i) * 1024;
    }
    {  // B chunk: 8 rows x 128B; lane covers (row=lane>>3, col16=lane&7)
      const int r = (w * 4 + i) * 8 + (lane >> 3);
      const int c = (lane & 7) ^ (r & 7);
      pb[i] = W + (size_t)r * NEMB + c * 8;
      lb[i] = (char*)Bsm + (w * 4 + i) * 1024;
    }
  }

  f32x4 acc[2][4];
  const f32x4 fz = {0.f, 0.f, 0.f, 0.f};
#pragma unroll
  for (int m = 0; m < 2; ++m)
#pragma unroll
    for (int n = 0; n < 4; ++n) acc[m][n] = fz;

  for (int tt = 0; tt < NEMB / 64; ++tt) {
    const int k0 = tt * 64;
    __syncthreads();   // previous compute done -> safe to overwrite tiles
#pragma unroll
    for (int i = 0; i < 4; ++i) async16(la[i], pa[i] + k0);
#pragma unroll
    for (int i = 0; i < 4; ++i) async16(lb[i], pb[i] + k0);
    __syncthreads();   // drain: tile tt resident

#pragma unroll
    for (int kk = 0; kk < 2; ++kk) {
      v8bf a[2], b[4];
#pragma unroll
      for (int m = 0; m < 2; ++m) {
        const int r = wm * 32 + m * 16 + lo;
        const int s = kk * 8 + hi * 2;             // fp32 16B-chunk pair s, s+1
        const char* rowp = (const char*)Asm + r * 256;
        F4 a0, a1;
        a0.v = *(const f32x4*)(rowp + (((s)     ^ (r & 7)) << 4));
        a1.v = *(const f32x4*)(rowp + (((s + 1) ^ (r & 7)) << 4));
        U8 u;
#pragma unroll
        for (int q = 0; q < 4; ++q) {
          u.b[q]     = (__bf16)a0.f[q];
          u.b[q + 4] = (__bf16)a1.f[q];
        }
        a[m] = u.v;
      }
#pragma unroll
      for (int n = 0; n < 4; ++n) {
        const int r = wn * 64 + n * 16 + lo;
        const int kc = kk * 4 + hi;
        b[n] = *(const v8bf*)((const char*)Bsm + r * 128 + ((kc ^ (r & 7)) << 4));
      }
#pragma unroll
      for (int m = 0; m < 2; ++m)
#pragma unroll
        for (int n = 0; n < 4; ++n)
          acc[m][n] = __builtin_amdgcn_mfma_f32_16x16x32_bf16(a[m], b[n], acc[m][n], 0, 0, 0);
    }
  }

#pragma unroll
  for (int n = 0; n < 4; ++n) {
    const int col = wn * 64 + n * 16 + lo;
    const float bi = bias[col];
#pragma unroll
    for (int m = 0; m < 2; ++m) {
#pragma unroll
      for (int r = 0; r < 4; ++r) {
        const int row = m0 + wm * 32 + m * 16 + hi * 4 + r;
        Out[(size_t)row * HD + col] = (__bf16)(acc[m][n][r] + bi);
      }
    }
  }
}

// ---------------- Flash attention (causal) ----------------
// grid: 8 batches * 32 q-tiles of 64 rows, 256 thr (4 waves x 16 q-rows)
__global__ __launch_bounds__(256) void attn_kernel(
    const __bf16* __restrict__ Qb, const __bf16* __restrict__ Kb,
    const __bf16* __restrict__ Vb, float* __restrict__ out)
{
  // XCD swizzle: each XCD gets one batch's 32 q-tiles -> K/V L2-resident
  const int bid0 = blockIdx.x;
  const int bid = ((bid0 & 7) << 5) + (bid0 >> 3);
  const int b = bid >> 5;
  const int qt = bid & 31;
  const int q0 = qt * 64;
  const int t = threadIdx.x;
  const int lane = t & 63;
  const int w = t >> 6;
  const int hi = lane >> 4, lo = lane & 15;

  __shared__ __bf16 Ksm[64 * 128];   // [key][d], swizzled
  __shared__ __bf16 Vtsm[128 * 64];  // [d][key], swizzled
  __shared__ __bf16 Psm[4][16 * 64]; // per-wave P tile [qrow][key], swizzled

  v8bf aQ[4];
  {
    const __bf16* qp = Qb + ((size_t)(b * SEQ + q0 + w * 16 + lo)) * HD + hi * 8;
#pragma unroll
    for (int kk = 0; kk < 4; ++kk) aQ[kk] = *(const v8bf*)(qp + kk * 32);
  }

  f32x4 accO[8];
  const f32x4 fz = {0.f, 0.f, 0.f, 0.f};
#pragma unroll
  for (int n = 0; n < 8; ++n) accO[n] = fz;
  float m_s[4], l_s[4];
#pragma unroll
  for (int r = 0; r < 4; ++r) { m_s[r] = -INFINITY; l_s[r] = 0.f; }

  const float scale = 0.022097086912079608f; // 1/sqrt(2048)

  for (int kv = 0; kv <= qt; ++kv) {
    __syncthreads();
    {
      const int key = t >> 2, dc = t & 3;
      const __bf16* kp = Kb + ((size_t)(b * SEQ + kv * 64 + key)) * HD + dc * 32;
      const int rb = key * 256;
      const int swk = (key & 7) << 4;
#pragma unroll
      for (int j = 0; j < 4; ++j) {
        v8bf v = *(const v8bf*)(kp + j * 8);
        *(v8bf*)((char*)Ksm + rb + ((dc * 64 + j * 16) ^ swk)) = v;
      }
    }
    {
      const int keyg = t >> 4, dg = t & 15;
      const __bf16* vp = Vb + ((size_t)(b * SEQ + kv * 64 + keyg * 4)) * HD + dg * 8;
      U8 vv[4];
#pragma unroll
      for (int j = 0; j < 4; ++j) vv[j].v = *(const v8bf*)(vp + (size_t)j * HD);
#pragma unroll
      for (int d = 0; d < 8; ++d) {
        ushort4 pk = make_ushort4(vv[0].e[d], vv[1].e[d], vv[2].e[d], vv[3].e[d]);
        const int row = dg * 8 + d;
        *(ushort4*)((char*)Vtsm + row * 128 + ((keyg * 8) ^ ((d & 7) << 4))) = pk;
      }
    }
    __syncthreads();

    f32x4 accS[4];
#pragma unroll
    for (int n = 0; n < 4; ++n) accS[n] = fz;
#pragma unroll
    for (int kk = 0; kk < 4; ++kk) {
      const int cb = kk * 64 + hi * 16;
      v8bf bk[4];
#pragma unroll
      for (int n = 0; n < 4; ++n) {
        const int r = n * 16 + lo;
        bk[n] = *(const v8bf*)((const char*)Ksm + r * 256 + (cb ^ ((r & 7) << 4)));
      }
#pragma unroll
      for (int n = 0; n < 4; ++n)
        accS[n] = __builtin_amdgcn_mfma_f32_16x16x32_bf16(aQ[kk], bk[n], accS[n], 0, 0, 0);
    }

    float s[4][4];
    const bool diag = (kv == qt);
#pragma unroll
    for (int n = 0; n < 4; ++n)
#pragma unroll
      for (int r = 0; r < 4; ++r) {
        float v = accS[n][r] * scale;
        if (diag) {
          const int key = kv * 64 + n * 16 + lo;
          const int qr = q0 + w * 16 + hi * 4 + r;
          if (key > qr) v = -INFINITY;
        }
        s[n][r] = v;
      }

    float mx[4];
#pragma unroll
    for (int r = 0; r < 4; ++r) {
      mx[r] = fmaxf(fmaxf(s[0][r], s[1][r]), fmaxf(s[2][r], s[3][r]));
#pragma unroll
      for (int off = 1; off < 16; off <<= 1)
        mx[r] = fmaxf(mx[r], __shfl_xor(mx[r], off));
    }
    float corr[4], p[4][4], rs[4];
#pragma unroll
    for (int r = 0; r < 4; ++r) {
      const float mnew = fmaxf(m_s[r], mx[r]);
      corr[r] = __expf(m_s[r] - mnew);
      m_s[r] = mnew;
      rs[r] = 0.f;
    }
#pragma unroll
    for (int n = 0; n < 4; ++n)
#pragma unroll
      for (int r = 0; r < 4; ++r) {
        p[n][r] = __expf(s[n][r] - m_s[r]);
        rs[r] += p[n][r];
      }
#pragma unroll
    for (int r = 0; r < 4; ++r) {
#pragma unroll
      for (int off = 1; off < 16; off <<= 1) rs[r] += __shfl_xor(rs[r], off);
      l_s[r] = l_s[r] * corr[r] + rs[r];
    }
#pragma unroll
    for (int n = 0; n < 8; ++n)
#pragma unroll
      for (int r = 0; r < 4; ++r) accO[n][r] *= corr[r];

#pragma unroll
    for (int n = 0; n < 4; ++n)
#pragma unroll
      for (int r = 0; r < 4; ++r) {
        const int row = hi * 4 + r;
        __bf16 h = (__bf16)p[n][r];
        *(unsigned short*)((char*)&Psm[w][0] + row * 128 +
                           (((n * 16 + lo) * 2) ^ ((row & 7) << 4))) =
            __builtin_bit_cast(unsigned short, h);
      }

#pragma unroll
    for (int k2 = 0; k2 < 2; ++k2) {
      const int cb = k2 * 64 + hi * 16;
      const v8bf aP = *(const v8bf*)((const char*)&Psm[w][0] + lo * 128 + (cb ^ ((lo & 7) << 4)));
#pragma unroll
      for (int n = 0; n < 8; ++n) {
        const int r = n * 16 + lo;
        const v8bf bv = *(const v8bf*)((const char*)Vtsm + r * 128 + (cb ^ ((r & 7) << 4)));
        accO[n] = __builtin_amdgcn_mfma_f32_16x16x32_bf16(aP, bv, accO[n], 0, 0, 0);
      }
    }
  }

#pragma unroll
  for (int r = 0; r < 4; ++r) {
    const float inv = 1.f / l_s[r];
    const int qr = q0 + w * 16 + hi * 4 + r;
    float* op = out + ((size_t)(b * SEQ + qr)) * HD + lo;
#pragma unroll
    for (int n = 0; n < 8; ++n) op[n * 16] = accO[n][r] * inv;
  }
}

extern "C" void kernel_launch(void* const* d_in, const int* in_sizes, int n_in,
                              void* d_out, int out_size, void* d_ws, size_t ws_size,
                              hipStream_t stream) {
  const float* x  = (const float*)d_in[0];
  const float* Wq = (const float*)d_in[1];
  const float* bq = (const float*)d_in[2];
  const float* Wk = (const float*)d_in[3];
  const float* bk = (const float*)d_in[4];
  const float* Wv = (const float*)d_in[5];
  const float* bv = (const float*)d_in[6];
  float* out = (float*)d_out;

  __bf16* Qb = (__bf16*)d_ws;                       // 16384x128 bf16 each
  __bf16* Kb = Qb + (size_t)BATCH * SEQ * HD;
  __bf16* Vb = Kb + (size_t)BATCH * SEQ * HD;
  __bf16* Wb = Vb + (size_t)BATCH * SEQ * HD;       // 3 x 128 x 2048 bf16

  wconv_kernel<<<dim3(3 * 64), dim3(256), 0, stream>>>(Wq, Wk, Wv, Wb);
  qkv_proj_kernel<<<dim3(256 * 3), dim3(256), 0, stream>>>(
      x, Wb, bq, bk, bv, Qb, Kb, Vb);
  attn_kernel<<<dim3(BATCH * (SEQ / 64)), dim3(256), 0, stream>>>(Qb, Kb, Vb, out);
}